// Round 1
// baseline (890.194 us; speedup 1.0000x reference)
//
#include <hip/hip_runtime.h>
#include <cmath>

#define N_IMG 128
#define MAX_R 36
#define N_CAP 128
#define MAX_W 32
#define DIM   512
#define NEGV  -1e30f

// ---------------------------------------------------------------------------
// Kernel A: per-image Gram matrices  G[i][a][b] = dot(imgs[i,a,:], imgs[i,b,:])
// Needed for den = ||att|| = sqrt(attn^T G attn) without materializing att.
// G lives in d_ws: 128*36*36 floats = 663552 B.
// ---------------------------------------------------------------------------
__global__ __launch_bounds__(256) void gram_kernel(const float* __restrict__ imgs,
                                                   float* __restrict__ G) {
    const int i = blockIdx.x;
    const int t = threadIdx.x;
    __shared__ float sImg[MAX_R][132];   // 128-float chunk + pad (float4-aligned)
    const float* base = imgs + (size_t)i * MAX_R * DIM;

    // 18 a-pairs x 12 b-triples = 216 active threads, 2x3 output tile each
    const int ap = t / 12;
    const int bt = t % 12;
    const bool active = ap < 18;
    float acc[2][3] = {};

    for (int ch = 0; ch < 4; ++ch) {
        for (int idx = t; idx < MAX_R * 32; idx += 256) {
            const int row = idx >> 5, col = idx & 31;
            *(float4*)&sImg[row][col * 4] =
                *(const float4*)(base + row * DIM + ch * 128 + col * 4);
        }
        __syncthreads();
        if (active) {
            #pragma unroll
            for (int k4 = 0; k4 < 32; ++k4) {
                float4 a0 = *(float4*)&sImg[ap * 2 + 0][k4 * 4];
                float4 a1 = *(float4*)&sImg[ap * 2 + 1][k4 * 4];
                float4 b0 = *(float4*)&sImg[bt * 3 + 0][k4 * 4];
                float4 b1 = *(float4*)&sImg[bt * 3 + 1][k4 * 4];
                float4 b2 = *(float4*)&sImg[bt * 3 + 2][k4 * 4];
                acc[0][0] += a0.x*b0.x + a0.y*b0.y + a0.z*b0.z + a0.w*b0.w;
                acc[0][1] += a0.x*b1.x + a0.y*b1.y + a0.z*b1.z + a0.w*b1.w;
                acc[0][2] += a0.x*b2.x + a0.y*b2.y + a0.z*b2.z + a0.w*b2.w;
                acc[1][0] += a1.x*b0.x + a1.y*b0.y + a1.z*b0.z + a1.w*b0.w;
                acc[1][1] += a1.x*b1.x + a1.y*b1.y + a1.z*b1.z + a1.w*b1.w;
                acc[1][2] += a1.x*b2.x + a1.y*b2.y + a1.z*b2.z + a1.w*b2.w;
            }
        }
        __syncthreads();
    }
    if (active) {
        float* g = G + (size_t)i * (MAX_R * MAX_R);
        #pragma unroll
        for (int x = 0; x < 2; ++x)
            #pragma unroll
            for (int y = 0; y < 3; ++y)
                g[(ap * 2 + x) * MAX_R + (bt * 3 + y)] = acc[x][y];
    }
}

// ---------------------------------------------------------------------------
// Kernel B: one block per (c,i) pair.
//  1. S[w][r] = dot(caps[c,w], imgs[i,r]) / 0.1   (LDS-staged chunked GEMM)
//  2. per valid w: top-5 threshold over valid r, softmax survivors,
//     num = 0.1 * sum p*s ; den = sqrt(p^T G p) + EPS ; out = num/den
//  invalid w -> -1.0
// ---------------------------------------------------------------------------
__global__ __launch_bounds__(256) void vsc_kernel(const float* __restrict__ imgs,
                                                  const float* __restrict__ caps,
                                                  const int* __restrict__ img_lens,
                                                  const int* __restrict__ cap_lens,
                                                  const float* __restrict__ G,
                                                  float* __restrict__ out) {
    const int bid = blockIdx.x;
    const int c = bid & (N_CAP - 1);
    const int i = bid >> 7;
    const int t = threadIdx.x;

    __shared__ float sCap[MAX_W][68];     // 64-float chunk + pad
    __shared__ float sImg[MAX_R][68];
    __shared__ float sS[MAX_W][37];       // sims (already /0.1)
    __shared__ float sG[MAX_R * MAX_R];

    const float* capBase = caps + (size_t)c * MAX_W * DIM;
    const float* imgBase = imgs + (size_t)i * MAX_R * DIM;

    // register tile: 4 w-rows x 2 r-cols per thread
    const int wq = (t & 7) * 4;           // w base
    const int rr = t >> 3;                // r0 in [0,32)
    const int r1 = (rr < MAX_R - 32) ? rr + 32 : rr;   // r1 (only valid rr<4)

    float acc[4][2] = {};

    for (int ch = 0; ch < 8; ++ch) {
        // caps chunk: 32 rows x 16 float4 = 512 float4 (2 per thread, coalesced)
        {
            int idx = t;
            int row = idx >> 4, col = idx & 15;
            *(float4*)&sCap[row][col * 4] =
                *(const float4*)(capBase + row * DIM + ch * 64 + col * 4);
            idx = t + 256;
            row = idx >> 4; col = idx & 15;
            *(float4*)&sCap[row][col * 4] =
                *(const float4*)(capBase + row * DIM + ch * 64 + col * 4);
        }
        // imgs chunk: 36 rows x 16 float4 = 576 float4
        for (int idx = t; idx < MAX_R * 16; idx += 256) {
            const int row = idx >> 4, col = idx & 15;
            *(float4*)&sImg[row][col * 4] =
                *(const float4*)(imgBase + row * DIM + ch * 64 + col * 4);
        }
        if (ch == 0) {   // stage Gram matrix once (covered by the barrier below)
            for (int idx = t; idx < MAX_R * MAX_R; idx += 256)
                sG[idx] = G[(size_t)i * MAX_R * MAX_R + idx];
        }
        __syncthreads();
        #pragma unroll
        for (int k4 = 0; k4 < 16; ++k4) {
            const float4 i0 = *(float4*)&sImg[rr][k4 * 4];
            const float4 i1 = *(float4*)&sImg[r1][k4 * 4];
            #pragma unroll
            for (int j = 0; j < 4; ++j) {
                const float4 cv = *(float4*)&sCap[wq + j][k4 * 4];
                acc[j][0] += cv.x*i0.x + cv.y*i0.y + cv.z*i0.z + cv.w*i0.w;
                acc[j][1] += cv.x*i1.x + cv.y*i1.y + cv.z*i1.z + cv.w*i1.w;
            }
        }
        __syncthreads();
    }

    #pragma unroll
    for (int j = 0; j < 4; ++j) {
        sS[wq + j][rr] = acc[j][0] / 0.1f;
        if (rr < MAX_R - 32) sS[wq + j][rr + 32] = acc[j][1] / 0.1f;
    }
    __syncthreads();

    if (t < MAX_W) {
        const int w = t;
        const int clen = cap_lens[c];
        float result = -1.0f;
        if (w < clen) {
            const int ilen = img_lens[i];   // guaranteed >= 6
            // top-5 (counting duplicates) over valid r
            float t0 = NEGV, t1 = NEGV, t2 = NEGV, t3 = NEGV, t4 = NEGV;
            for (int r = 0; r < ilen; ++r) {
                const float v = sS[w][r];
                if (v > t4) {
                    if (v > t0)      { t4=t3; t3=t2; t2=t1; t1=t0; t0=v; }
                    else if (v > t1) { t4=t3; t3=t2; t2=t1; t1=v; }
                    else if (v > t2) { t4=t3; t3=t2; t2=v; }
                    else if (v > t3) { t4=t3; t3=v; }
                    else             { t4=v; }
                }
            }
            const float kth = t4, m = t0;
            // survivors (s >= kth); sum over ALL survivors, cap stored at 8
            int   idxs[8];
            float pv[8];
            int cnt = 0;
            float sum = 0.f;
            for (int r = 0; r < ilen; ++r) {
                const float v = sS[w][r];
                if (v >= kth) {
                    const float e = expf(v - m);
                    sum += e;
                    if (cnt < 8) { idxs[cnt] = r; pv[cnt] = e; ++cnt; }
                }
            }
            const float inv = 1.0f / sum;
            float num = 0.f, den2 = 0.f;
            for (int a = 0; a < cnt; ++a) {
                const float pa = pv[a] * inv;
                num += pa * sS[w][idxs[a]];
                for (int b = 0; b < cnt; ++b)
                    den2 += pa * (pv[b] * inv) * sG[idxs[a] * MAX_R + idxs[b]];
            }
            num *= 0.1f;
            const float den = sqrtf(den2) + (-1e-8f);
            result = num / den;
        }
        out[((size_t)i * N_CAP + c) * MAX_W + w] = result;
    }
}

extern "C" void kernel_launch(void* const* d_in, const int* in_sizes, int n_in,
                              void* d_out, int out_size, void* d_ws, size_t ws_size,
                              hipStream_t stream) {
    const float* imgs     = (const float*)d_in[0];
    const float* caps     = (const float*)d_in[1];
    const int*   img_lens = (const int*)d_in[2];
    const int*   cap_lens = (const int*)d_in[3];
    float* out = (float*)d_out;
    float* G   = (float*)d_ws;   // needs 128*36*36*4 = 663552 B of scratch

    gram_kernel<<<N_IMG, 256, 0, stream>>>(imgs, G);
    vsc_kernel<<<N_IMG * N_CAP, 256, 0, stream>>>(imgs, caps, img_lens, cap_lens, G, out);
}

// Round 2
// 205.248 us; speedup vs baseline: 4.3372x; 4.3372x over previous
//
#include <hip/hip_runtime.h>
#include <cmath>

#define N_IMG 128
#define MAX_R 36
#define N_CAP 128
#define MAX_W 32
#define DIM   512
#define NEGV  -1e30f

typedef unsigned short u16;
typedef unsigned int   u32;
typedef __attribute__((ext_vector_type(8))) short short8;
typedef __attribute__((ext_vector_type(4))) float f32x4;

#define NI_ELEMS (N_IMG * MAX_R * DIM)   // 2359296
#define NC_ELEMS (N_CAP * MAX_W * DIM)   // 2097152

__device__ __forceinline__ u16 f2bf(float x) {
    u32 u = __float_as_uint(x);
    u32 r = u + 0x7fffu + ((u >> 16) & 1u);
    return (u16)(r >> 16);
}
__device__ __forceinline__ float bf2f(u16 h) {
    return __uint_as_float(((u32)h) << 16);
}

// ---------------------------------------------------------------------------
// Kernel 0: fp32 -> (hi, lo) bf16 split for imgs and caps.
// ---------------------------------------------------------------------------
__global__ __launch_bounds__(256) void convert_kernel(const float* __restrict__ imgs,
                                                      const float* __restrict__ caps,
                                                      u16* __restrict__ imgs_hi,
                                                      u16* __restrict__ imgs_lo,
                                                      u16* __restrict__ caps_hi,
                                                      u16* __restrict__ caps_lo) {
    const size_t ni4 = NI_ELEMS / 4;
    const size_t total4 = (NI_ELEMS + NC_ELEMS) / 4;
    const size_t stride = (size_t)gridDim.x * blockDim.x;
    for (size_t p = (size_t)blockIdx.x * blockDim.x + threadIdx.x; p < total4; p += stride) {
        const bool isImg = p < ni4;
        const float4 v = isImg ? ((const float4*)imgs)[p] : ((const float4*)caps)[p - ni4];
        u16 h0 = f2bf(v.x), h1 = f2bf(v.y), h2 = f2bf(v.z), h3 = f2bf(v.w);
        u16 l0 = f2bf(v.x - bf2f(h0)), l1 = f2bf(v.y - bf2f(h1));
        u16 l2 = f2bf(v.z - bf2f(h2)), l3 = f2bf(v.w - bf2f(h3));
        uint2 hv, lv;
        hv.x = (u32)h0 | ((u32)h1 << 16);  hv.y = (u32)h2 | ((u32)h3 << 16);
        lv.x = (u32)l0 | ((u32)l1 << 16);  lv.y = (u32)l2 | ((u32)l3 << 16);
        if (isImg) {
            *(uint2*)(imgs_hi + p * 4) = hv;
            *(uint2*)(imgs_lo + p * 4) = lv;
        } else {
            const size_t q = (p - ni4) * 4;
            *(uint2*)(caps_hi + q) = hv;
            *(uint2*)(caps_lo + q) = lv;
        }
    }
}

// ---------------------------------------------------------------------------
// Kernel A: per-image Gram matrices G[i][a][b] = dot(imgs[i,a,:], imgs[i,b,:])
// ---------------------------------------------------------------------------
__global__ __launch_bounds__(256) void gram_kernel(const float* __restrict__ imgs,
                                                   float* __restrict__ G) {
    const int i = blockIdx.x;
    const int t = threadIdx.x;
    __shared__ float sImg[MAX_R][132];
    const float* base = imgs + (size_t)i * MAX_R * DIM;

    const int ap = t / 12;
    const int bt = t % 12;
    const bool active = ap < 18;
    float acc[2][3] = {};

    for (int ch = 0; ch < 4; ++ch) {
        for (int idx = t; idx < MAX_R * 32; idx += 256) {
            const int row = idx >> 5, col = idx & 31;
            *(float4*)&sImg[row][col * 4] =
                *(const float4*)(base + row * DIM + ch * 128 + col * 4);
        }
        __syncthreads();
        if (active) {
            #pragma unroll
            for (int k4 = 0; k4 < 32; ++k4) {
                float4 a0 = *(float4*)&sImg[ap * 2 + 0][k4 * 4];
                float4 a1 = *(float4*)&sImg[ap * 2 + 1][k4 * 4];
                float4 b0 = *(float4*)&sImg[bt * 3 + 0][k4 * 4];
                float4 b1 = *(float4*)&sImg[bt * 3 + 1][k4 * 4];
                float4 b2 = *(float4*)&sImg[bt * 3 + 2][k4 * 4];
                acc[0][0] += a0.x*b0.x + a0.y*b0.y + a0.z*b0.z + a0.w*b0.w;
                acc[0][1] += a0.x*b1.x + a0.y*b1.y + a0.z*b1.z + a0.w*b1.w;
                acc[0][2] += a0.x*b2.x + a0.y*b2.y + a0.z*b2.z + a0.w*b2.w;
                acc[1][0] += a1.x*b0.x + a1.y*b0.y + a1.z*b0.z + a1.w*b0.w;
                acc[1][1] += a1.x*b1.x + a1.y*b1.y + a1.z*b1.z + a1.w*b1.w;
                acc[1][2] += a1.x*b2.x + a1.y*b2.y + a1.z*b2.z + a1.w*b2.w;
            }
        }
        __syncthreads();
    }
    if (active) {
        float* g = G + (size_t)i * (MAX_R * MAX_R);
        #pragma unroll
        for (int x = 0; x < 2; ++x)
            #pragma unroll
            for (int y = 0; y < 3; ++y)
                g[(ap * 2 + x) * MAX_R + (bt * 3 + y)] = acc[x][y];
    }
}

// ---------------------------------------------------------------------------
// Kernel B: one block per (image, group-of-4-caps).
//   MFMA GEMM: S[128 w-rows][36 r] via 3-pass bf16 hi/lo split (fp32-accurate)
//   wave q handles cap q of the group (rows q*32..q*32+31).
//   Then per-w top-5 / softmax / num / den(Gram) postprocess.
// ---------------------------------------------------------------------------
__global__ __launch_bounds__(256) void vsc_mfma_kernel(const u16* __restrict__ imgs_hi,
                                                       const u16* __restrict__ imgs_lo,
                                                       const u16* __restrict__ caps_hi,
                                                       const u16* __restrict__ caps_lo,
                                                       const int* __restrict__ img_lens,
                                                       const int* __restrict__ cap_lens,
                                                       const float* __restrict__ G,
                                                       float* __restrict__ out) {
    const int bid = blockIdx.x;
    const int i  = bid >> 5;          // image
    const int cg = bid & 31;          // cap group (4 caps)
    const int t  = threadIdx.x;
    const int wid  = t >> 6;          // wave 0..3
    const int lane = t & 63;

    __shared__ u16 sA_hi[128][32];    // caps chunk (hi)
    __shared__ u16 sA_lo[128][32];
    __shared__ u16 sB_hi[48][32];     // imgs chunk (hi); rows 36..47 read as garbage (discarded cols)
    __shared__ u16 sB_lo[48][32];
    __shared__ float sS[128][37];     // sims / TEMPERATURE
    __shared__ float sG[MAX_R * MAX_R];

    // stage Gram matrix once
    for (int idx = t; idx < MAX_R * MAX_R; idx += 256)
        sG[idx] = G[(size_t)i * (MAX_R * MAX_R) + idx];

    f32x4 acc[2][3];
    #pragma unroll
    for (int mt = 0; mt < 2; ++mt)
        #pragma unroll
        for (int nt = 0; nt < 3; ++nt)
            acc[mt][nt] = (f32x4){0.f, 0.f, 0.f, 0.f};

    const size_t capRowBase = (size_t)cg * 128;   // global cap-row of A row 0
    const size_t imgBase    = (size_t)i * MAX_R;

    for (int kb = 0; kb < 16; ++kb) {
        const int k0 = kb * 32;
        // ---- stage A (caps): 128 rows x 32 k, hi+lo. 512 16B-loads each.
        #pragma unroll
        for (int rep = 0; rep < 2; ++rep) {
            const int idx = t + rep * 256;
            const int row = idx >> 2, kb8 = idx & 3;
            const int blk = kb8 ^ ((row >> 1) & 3);
            const size_t goff = (capRowBase + row) * DIM + k0 + kb8 * 8;
            *(uint4*)&sA_hi[row][blk * 8] = *(const uint4*)(caps_hi + goff);
            *(uint4*)&sA_lo[row][blk * 8] = *(const uint4*)(caps_lo + goff);
        }
        // ---- stage B (imgs): 36 rows x 32 k, hi then lo (288 16B-loads total)
        for (int idx = t; idx < 288; idx += 256) {
            const int a = idx >= 144;
            const int j = idx - a * 144;
            const int row = j >> 2, kb8 = j & 3;
            const int blk = kb8 ^ ((row >> 1) & 3);
            const size_t goff = (imgBase + row) * DIM + k0 + kb8 * 8;
            const uint4 v = *(const uint4*)((a ? imgs_lo : imgs_hi) + goff);
            *(uint4*)((a ? &sB_lo[row][0] : &sB_hi[row][0]) + blk * 8) = v;
        }
        __syncthreads();

        // ---- fragments
        const int kblk = lane >> 4;          // logical k-block 0..3
        short8 ah[2], al[2], bh[3], bl[3];
        #pragma unroll
        for (int mt = 0; mt < 2; ++mt) {
            const int row = wid * 32 + mt * 16 + (lane & 15);
            const int blk = kblk ^ ((row >> 1) & 3);
            ah[mt] = *(const short8*)&sA_hi[row][blk * 8];
            al[mt] = *(const short8*)&sA_lo[row][blk * 8];
        }
        #pragma unroll
        for (int nt = 0; nt < 3; ++nt) {
            const int r = nt * 16 + (lane & 15);
            const int blk = kblk ^ ((r >> 1) & 3);
            bh[nt] = *(const short8*)&sB_hi[r][blk * 8];
            bl[nt] = *(const short8*)&sB_lo[r][blk * 8];
        }
        // ---- 3-pass MFMA: hi*hi + hi*lo + lo*hi
        #pragma unroll
        for (int mt = 0; mt < 2; ++mt)
            #pragma unroll
            for (int nt = 0; nt < 3; ++nt) {
                acc[mt][nt] = __builtin_amdgcn_mfma_f32_16x16x32_bf16(ah[mt], bh[nt], acc[mt][nt], 0, 0, 0);
                acc[mt][nt] = __builtin_amdgcn_mfma_f32_16x16x32_bf16(ah[mt], bl[nt], acc[mt][nt], 0, 0, 0);
                acc[mt][nt] = __builtin_amdgcn_mfma_f32_16x16x32_bf16(al[mt], bh[nt], acc[mt][nt], 0, 0, 0);
            }
        __syncthreads();
    }

    // ---- write sims to LDS (already * 1/TEMPERATURE)
    #pragma unroll
    for (int mt = 0; mt < 2; ++mt)
        #pragma unroll
        for (int nt = 0; nt < 3; ++nt) {
            const int col = nt * 16 + (lane & 15);
            if (col < MAX_R) {
                #pragma unroll
                for (int reg = 0; reg < 4; ++reg) {
                    const int row = wid * 32 + mt * 16 + (lane >> 4) * 4 + reg;
                    sS[row][col] = acc[mt][nt][reg] * 10.f;
                }
            }
        }
    __syncthreads();

    // ---- postprocess: one thread per (cap-in-group, w)
    if (t < 128) {
        const int q = t >> 5;           // cap within group
        const int w = t & 31;
        const int c = cg * 4 + q;
        const int clen = cap_lens[c];
        float result = -1.0f;
        if (w < clen) {
            const int ilen = img_lens[i];   // >= 6 by construction
            float t0 = NEGV, t1 = NEGV, t2 = NEGV, t3 = NEGV, t4 = NEGV;
            for (int r = 0; r < ilen; ++r) {
                const float v = sS[t][r];
                if (v > t4) {
                    if (v > t0)      { t4=t3; t3=t2; t2=t1; t1=t0; t0=v; }
                    else if (v > t1) { t4=t3; t3=t2; t2=t1; t1=v; }
                    else if (v > t2) { t4=t3; t3=t2; t2=v; }
                    else if (v > t3) { t4=t3; t3=v; }
                    else             { t4=v; }
                }
            }
            const float kth = t4, m = t0;
            int   idxs[8];
            float pv[8];
            int cnt = 0;
            float sum = 0.f;
            for (int r = 0; r < ilen; ++r) {
                const float v = sS[t][r];
                if (v >= kth) {
                    const float e = expf(v - m);
                    sum += e;
                    if (cnt < 8) { idxs[cnt] = r; pv[cnt] = e; ++cnt; }
                }
            }
            const float inv = 1.0f / sum;
            float num = 0.f, den2 = 0.f;
            for (int a = 0; a < cnt; ++a) {
                const float pa = pv[a] * inv;
                num += pa * sS[t][idxs[a]];
                for (int b = 0; b < cnt; ++b)
                    den2 += pa * (pv[b] * inv) * sG[idxs[a] * MAX_R + idxs[b]];
            }
            num *= 0.1f;
            const float den = sqrtf(den2) + (-1e-8f);
            result = num / den;
        }
        out[((size_t)i * N_CAP + c) * MAX_W + w] = result;
    }
}

extern "C" void kernel_launch(void* const* d_in, const int* in_sizes, int n_in,
                              void* d_out, int out_size, void* d_ws, size_t ws_size,
                              hipStream_t stream) {
    const float* imgs     = (const float*)d_in[0];
    const float* caps     = (const float*)d_in[1];
    const int*   img_lens = (const int*)d_in[2];
    const int*   cap_lens = (const int*)d_in[3];
    float* out = (float*)d_out;

    // d_ws layout
    float* G = (float*)d_ws;                                   // 663552 B
    u16* imgs_hi = (u16*)((char*)d_ws + 663552);               // 4718592 B
    u16* imgs_lo = imgs_hi + NI_ELEMS;                         // 4718592 B
    u16* caps_hi = imgs_lo + NI_ELEMS;                         // 4194304 B
    u16* caps_lo = caps_hi + NC_ELEMS;                         // 4194304 B

    convert_kernel<<<2048, 256, 0, stream>>>(imgs, caps, imgs_hi, imgs_lo, caps_hi, caps_lo);
    gram_kernel<<<N_IMG, 256, 0, stream>>>(imgs, G);
    vsc_mfma_kernel<<<N_IMG * 32, 256, 0, stream>>>(imgs_hi, imgs_lo, caps_hi, caps_lo,
                                                    img_lens, cap_lens, G, out);
}

// Round 3
// 164.879 us; speedup vs baseline: 5.3991x; 1.2448x over previous
//
#include <hip/hip_runtime.h>
#include <cmath>

#define N_IMG 128
#define MAX_R 36
#define N_CAP 128
#define MAX_W 32
#define DIM   512
#define NEGV  -1e30f

typedef unsigned short u16;
typedef unsigned int   u32;
typedef __attribute__((ext_vector_type(8))) short short8;
typedef __attribute__((ext_vector_type(4))) float f32x4;

#define NI_ELEMS (N_IMG * MAX_R * DIM)   // 2359296
#define NC_ELEMS (N_CAP * MAX_W * DIM)   // 2097152

// tiled buffer geometry
#define A_CHUNK 8192   // u16 per (cg,kb): [2 h][128 row][32 k]
#define B_CHUNK 3072   // u16 per (i ,kb): [2 h][48 row][32 k]

__device__ __forceinline__ u16 f2bf(float x) {
    u32 u = __float_as_uint(x);
    u32 r = u + 0x7fffu + ((u >> 16) & 1u);
    return (u16)(r >> 16);
}
__device__ __forceinline__ float bf2f(u16 h) {
    return __uint_as_float(((u32)h) << 16);
}

__device__ __forceinline__ void gload_lds16(const void* g, void* l) {
    __builtin_amdgcn_global_load_lds(
        (const __attribute__((address_space(1))) void*)g,
        (__attribute__((address_space(3))) void*)l, 16, 0, 0);
}

// ---------------------------------------------------------------------------
// Kernel 0: fp32 -> (hi,lo) bf16 split, written PRE-TILED + PRE-SWIZZLED so the
// GEMM kernel can stage each k-step with linear global_load_lds.
// ---------------------------------------------------------------------------
__global__ __launch_bounds__(256) void convert_kernel(const float* __restrict__ imgs,
                                                      const float* __restrict__ caps,
                                                      u16* __restrict__ imgsT,
                                                      u16* __restrict__ capsT) {
    const size_t ni4 = NI_ELEMS / 4;
    const size_t total4 = (NI_ELEMS + NC_ELEMS) / 4;
    const size_t stride = (size_t)gridDim.x * blockDim.x;
    for (size_t p = (size_t)blockIdx.x * blockDim.x + threadIdx.x; p < total4; p += stride) {
        const bool isImg = p < ni4;
        const float4 v = isImg ? ((const float4*)imgs)[p] : ((const float4*)caps)[p - ni4];
        u16 h0 = f2bf(v.x), h1 = f2bf(v.y), h2 = f2bf(v.z), h3 = f2bf(v.w);
        u16 l0 = f2bf(v.x - bf2f(h0)), l1 = f2bf(v.y - bf2f(h1));
        u16 l2 = f2bf(v.z - bf2f(h2)), l3 = f2bf(v.w - bf2f(h3));
        uint2 hv, lv;
        hv.x = (u32)h0 | ((u32)h1 << 16);  hv.y = (u32)h2 | ((u32)h3 << 16);
        lv.x = (u32)l0 | ((u32)l1 << 16);  lv.y = (u32)l2 | ((u32)l3 << 16);
        if (isImg) {
            const int e = (int)(p * 4);
            const int i = e / (MAX_R * DIM);
            const int rem = e - i * (MAX_R * DIM);
            const int r = rem >> 9, k = rem & 511;
            const int kb = k >> 5, k8 = (k >> 3) & 3, kpos = k & 7;
            const int blk = k8 ^ ((r >> 1) & 3);
            const size_t d = (size_t)(i * 16 + kb) * 2 * 1536 + r * 32 + blk * 8 + kpos;
            *(uint2*)(imgsT + d) = hv;
            *(uint2*)(imgsT + d + 1536) = lv;
        } else {
            const int e = (int)((p - ni4) * 4);
            const int R = e >> 9, k = e & 511;
            const int cg = R >> 7, row = R & 127;
            const int kb = k >> 5, k8 = (k >> 3) & 3, kpos = k & 7;
            const int blk = k8 ^ ((row >> 1) & 3);
            const size_t d = (size_t)(cg * 16 + kb) * 2 * 4096 + row * 32 + blk * 8 + kpos;
            *(uint2*)(capsT + d) = hv;
            *(uint2*)(capsT + d + 4096) = lv;
        }
    }
}

// ---------------------------------------------------------------------------
// Kernel A: per-image Gram matrices G[i][a][b] = dot(imgs[i,a,:], imgs[i,b,:])
// ---------------------------------------------------------------------------
__global__ __launch_bounds__(256) void gram_kernel(const float* __restrict__ imgs,
                                                   float* __restrict__ G) {
    const int i = blockIdx.x;
    const int t = threadIdx.x;
    __shared__ float sImg[MAX_R][132];
    const float* base = imgs + (size_t)i * MAX_R * DIM;

    const int ap = t / 12;
    const int bt = t % 12;
    const bool active = ap < 18;
    float acc[2][3] = {};

    for (int ch = 0; ch < 4; ++ch) {
        for (int idx = t; idx < MAX_R * 32; idx += 256) {
            const int row = idx >> 5, col = idx & 31;
            *(float4*)&sImg[row][col * 4] =
                *(const float4*)(base + row * DIM + ch * 128 + col * 4);
        }
        __syncthreads();
        if (active) {
            #pragma unroll
            for (int k4 = 0; k4 < 32; ++k4) {
                float4 a0 = *(float4*)&sImg[ap * 2 + 0][k4 * 4];
                float4 a1 = *(float4*)&sImg[ap * 2 + 1][k4 * 4];
                float4 b0 = *(float4*)&sImg[bt * 3 + 0][k4 * 4];
                float4 b1 = *(float4*)&sImg[bt * 3 + 1][k4 * 4];
                float4 b2 = *(float4*)&sImg[bt * 3 + 2][k4 * 4];
                acc[0][0] += a0.x*b0.x + a0.y*b0.y + a0.z*b0.z + a0.w*b0.w;
                acc[0][1] += a0.x*b1.x + a0.y*b1.y + a0.z*b1.z + a0.w*b1.w;
                acc[0][2] += a0.x*b2.x + a0.y*b2.y + a0.z*b2.z + a0.w*b2.w;
                acc[1][0] += a1.x*b0.x + a1.y*b0.y + a1.z*b0.z + a1.w*b0.w;
                acc[1][1] += a1.x*b1.x + a1.y*b1.y + a1.z*b1.z + a1.w*b1.w;
                acc[1][2] += a1.x*b2.x + a1.y*b2.y + a1.z*b2.z + a1.w*b2.w;
            }
        }
        __syncthreads();
    }
    if (active) {
        float* g = G + (size_t)i * (MAX_R * MAX_R);
        #pragma unroll
        for (int x = 0; x < 2; ++x)
            #pragma unroll
            for (int y = 0; y < 3; ++y)
                g[(ap * 2 + x) * MAX_R + (bt * 3 + y)] = acc[x][y];
    }
}

// ---------------------------------------------------------------------------
// Kernel B: one block per (image, 4-cap group). Double-buffered LDS,
// global_load_lds staging, stage(next) issued before compute(cur).
// ---------------------------------------------------------------------------
__global__ __launch_bounds__(256) void vsc_mfma_kernel(const u16* __restrict__ imgsT,
                                                       const u16* __restrict__ capsT,
                                                       const int* __restrict__ img_lens,
                                                       const int* __restrict__ cap_lens,
                                                       const float* __restrict__ G,
                                                       float* __restrict__ out) {
    const int bid = blockIdx.x;
    const int i  = bid >> 5;          // image
    const int cg = bid & 31;          // cap group (4 caps = 128 A rows)
    const int t  = threadIdx.x;
    const int wid  = t >> 6;
    const int lane = t & 63;
    const int l15  = lane & 15;
    const int kblk = lane >> 4;

    // buf layout (bytes): [0,8192) A_hi | [8192,16384) A_lo
    //                     [16384,19456) B_hi | [19456,22528) B_lo
    __shared__ __align__(16) char sBuf[2][22528];
    __shared__ float sG[MAX_R * MAX_R];

    for (int idx = t; idx < MAX_R * MAX_R; idx += 256)
        sG[idx] = G[(size_t)i * (MAX_R * MAX_R) + idx];

    f32x4 acc[2][3];
    #pragma unroll
    for (int mt = 0; mt < 2; ++mt)
        #pragma unroll
        for (int nt = 0; nt < 3; ++nt)
            acc[mt][nt] = (f32x4){0.f, 0.f, 0.f, 0.f};

    const char* gA0 = (const char*)(capsT + (size_t)cg * 16 * 2 * 4096);
    const char* gB0 = (const char*)(imgsT + (size_t)i  * 16 * 2 * 1536);

    // stage one k-step (A: 16KB, B: 6KB) into buf
    auto stage = [&](int kb, char* buf) {
        const char* ga = gA0 + (size_t)kb * (A_CHUNK * 2);
        const char* gb = gB0 + (size_t)kb * (B_CHUNK * 2);
        #pragma unroll
        for (int j = 0; j < 4; ++j) {
            const int off = j * 4096 + wid * 1024;
            gload_lds16(ga + off + lane * 16, buf + off);
        }
        {
            const int off = wid * 1024;
            gload_lds16(gb + off + lane * 16, buf + 16384 + off);
        }
        if (wid < 2) {
            const int off = 4096 + wid * 1024;
            gload_lds16(gb + off + lane * 16, buf + 16384 + off);
        }
    };

    stage(0, sBuf[0]);
    __syncthreads();

    for (int kb = 0; kb < 16; ++kb) {
        char* cur = sBuf[kb & 1];
        if (kb < 15) stage(kb + 1, sBuf[(kb + 1) & 1]);

        short8 ah[2], al[2], bh[3], bl[3];
        #pragma unroll
        for (int mt = 0; mt < 2; ++mt) {
            const int row = wid * 32 + mt * 16 + l15;
            const int blk = kblk ^ ((row >> 1) & 3);
            ah[mt] = *(const short8*)(cur + row * 64 + blk * 16);
            al[mt] = *(const short8*)(cur + 8192 + row * 64 + blk * 16);
        }
        #pragma unroll
        for (int nt = 0; nt < 3; ++nt) {
            const int r = nt * 16 + l15;
            const int blk = kblk ^ ((r >> 1) & 3);
            bh[nt] = *(const short8*)(cur + 16384 + r * 64 + blk * 16);
            bl[nt] = *(const short8*)(cur + 19456 + r * 64 + blk * 16);
        }
        #pragma unroll
        for (int mt = 0; mt < 2; ++mt)
            #pragma unroll
            for (int nt = 0; nt < 3; ++nt)
                acc[mt][nt] = __builtin_amdgcn_mfma_f32_16x16x32_bf16(ah[mt], bh[nt], acc[mt][nt], 0, 0, 0);
        #pragma unroll
        for (int mt = 0; mt < 2; ++mt)
            #pragma unroll
            for (int nt = 0; nt < 3; ++nt)
                acc[mt][nt] = __builtin_amdgcn_mfma_f32_16x16x32_bf16(ah[mt], bl[nt], acc[mt][nt], 0, 0, 0);
        #pragma unroll
        for (int mt = 0; mt < 2; ++mt)
            #pragma unroll
            for (int nt = 0; nt < 3; ++nt)
                acc[mt][nt] = __builtin_amdgcn_mfma_f32_16x16x32_bf16(al[mt], bh[nt], acc[mt][nt], 0, 0, 0);

        __syncthreads();
    }

    // ---- sims -> LDS overlay (on sBuf[0]); value already / TEMPERATURE
    float (*sS)[37] = (float (*)[37])&sBuf[0][0];   // 128 x 37 x 4B = 18944 B
    #pragma unroll
    for (int mt = 0; mt < 2; ++mt)
        #pragma unroll
        for (int nt = 0; nt < 3; ++nt) {
            const int col = nt * 16 + l15;
            if (col < MAX_R) {
                #pragma unroll
                for (int reg = 0; reg < 4; ++reg) {
                    const int row = wid * 32 + mt * 16 + (lane >> 4) * 4 + reg;
                    sS[row][col] = acc[mt][nt][reg] * 10.f;
                }
            }
        }
    __syncthreads();

    // ---- postprocess: one thread per (cap-in-group, w)
    if (t < 128) {
        const int q = t >> 5;
        const int w = t & 31;
        const int c = cg * 4 + q;
        const int clen = cap_lens[c];
        float result = -1.0f;
        if (w < clen) {
            const int ilen = img_lens[i];   // >= 6 by construction
            float t0 = NEGV, t1 = NEGV, t2 = NEGV, t3 = NEGV, t4 = NEGV;
            for (int r = 0; r < ilen; ++r) {
                const float v = sS[t][r];
                if (v > t4) {
                    if (v > t0)      { t4=t3; t3=t2; t2=t1; t1=t0; t0=v; }
                    else if (v > t1) { t4=t3; t3=t2; t2=t1; t1=v; }
                    else if (v > t2) { t4=t3; t3=t2; t2=v; }
                    else if (v > t3) { t4=t3; t3=v; }
                    else             { t4=v; }
                }
            }
            const float kth = t4, m = t0;
            int   idxs[8];
            float pv[8];
            int cnt = 0;
            float sum = 0.f;
            for (int r = 0; r < ilen; ++r) {
                const float v = sS[t][r];
                if (v >= kth) {
                    const float e = expf(v - m);
                    sum += e;
                    if (cnt < 8) { idxs[cnt] = r; pv[cnt] = e; ++cnt; }
                }
            }
            const float inv = 1.0f / sum;
            float num = 0.f, den2 = 0.f;
            for (int a = 0; a < cnt; ++a) {
                const float pa = pv[a] * inv;
                num += pa * sS[t][idxs[a]];
                for (int b = 0; b < cnt; ++b)
                    den2 += pa * (pv[b] * inv) * sG[idxs[a] * MAX_R + idxs[b]];
            }
            num *= 0.1f;
            const float den = sqrtf(den2) + (-1e-8f);
            result = num / den;
        }
        out[((size_t)i * N_CAP + c) * MAX_W + w] = result;
    }
}

extern "C" void kernel_launch(void* const* d_in, const int* in_sizes, int n_in,
                              void* d_out, int out_size, void* d_ws, size_t ws_size,
                              hipStream_t stream) {
    const float* imgs     = (const float*)d_in[0];
    const float* caps     = (const float*)d_in[1];
    const int*   img_lens = (const int*)d_in[2];
    const int*   cap_lens = (const int*)d_in[3];
    float* out = (float*)d_out;

    // d_ws layout
    float* G = (float*)d_ws;                                   // 663552 B
    u16* imgsT = (u16*)((char*)d_ws + 663552);                 // 128*16*2*1536 u16 = 12.6 MB
    u16* capsT = imgsT + (size_t)N_IMG * 16 * 2 * 1536;        // 32*16*2*4096  u16 =  8.4 MB

    convert_kernel<<<2048, 256, 0, stream>>>(imgs, caps, imgsT, capsT);
    gram_kernel<<<N_IMG, 256, 0, stream>>>(imgs, G);
    vsc_mfma_kernel<<<N_IMG * 32, 256, 0, stream>>>(imgsT, capsT, img_lens, cap_lens, G, out);
}